// Round 16
// baseline (2262.460 us; speedup 1.0000x reference)
//
#include <hip/hip_runtime.h>
#include <cstddef>

// ---------------------------------------------------------------------------
// RNNModel round 16: concurrent decoder, spill-free retry. Grid 506 = 256 rnn
// blocks (round-15 per-wave-poll recurrence, unchanged) + 250 decoder blocks
// that poll flg1 and decode ready 2-timestep x 128-col chunks of hs1@dec_W^T.
// __launch_bounds__(512,1) (VGPR=128 codegen); decoder uses acc[2][4] (32
// VGPR) + on-the-fly dec_W conversion so ws need stays at the PROVEN 129.6MB
// round-12 layout (all loop-lifetime state in d_ws; decode writes d_out live).
// Waits one-directional -> no deadlock; worst case = serialized (round-15 perf).
// h exchange: inline-asm sc0/sc1 bypass. Flags: relaxed agent atomics.
// Gate perm_g: col n <-> W row ((n>>4)&3)*1024+(n>>6)*16+(n&15).
// Chunk perm: 16B chunk c in each 128B segment stored at c^(row&7).
// ---------------------------------------------------------------------------

static constexpr int T_ = 50, B_ = 64, E_ = 1024, H_ = 1024, V_ = 32000;
static constexpr int G_ = 4096;

typedef unsigned short u16;
typedef unsigned int u32;
typedef unsigned long long u64;
typedef __attribute__((ext_vector_type(8))) short bf16x8;
typedef __attribute__((ext_vector_type(8))) unsigned short u16x8;
typedef __attribute__((ext_vector_type(4))) float f32x4;

__device__ __forceinline__ int perm_g(int n) {
  return ((n >> 4) & 3) * H_ + (n >> 6) * 16 + (n & 15);
}
__device__ __forceinline__ u16 bf16_rn(float x) {
  union { float f; unsigned u; } a; a.f = x;
  unsigned r = a.u + 0x7fffu + ((a.u >> 16) & 1u);
  return (u16)(r >> 16);
}
__device__ __forceinline__ float bf16_f(u16 h) {
  union { float f; unsigned u; } a; a.u = ((unsigned)h) << 16;
  return a.f;
}
__device__ __forceinline__ float sigm(float x) { return 1.f / (1.f + __expf(-x)); }

__global__ void fill_zero(float* p, int n) {
  int i = blockIdx.x * blockDim.x + threadIdx.x;
  if (i < n) p[i] = 0.f;
}
__global__ void bias_perm(const float* a, const float* b, float* dst) {
  int n = blockIdx.x * 256 + threadIdx.x;
  int s = perm_g(n);
  dst[n] = a[s] + b[s];
}

// f32 -> interleaved hi|lo bf16 [rows x 2048 u16] with chunk permute.
__global__ void conv_w(const float* __restrict__ src, int srcld, int coloff,
                       const int* __restrict__ gidx, int PERM, int rows,
                       u16* __restrict__ dst) {
  int idx = blockIdx.x * 256 + threadIdx.x;
  int r = idx >> 7, kc = (idx & 127) << 3;
  if (r >= rows) return;
  int s = gidx ? gidx[r] : (PERM ? perm_g(r) : r);
  const float* p = src + (size_t)s * srcld + coloff + kc;
  float4 v0 = *(const float4*)p, v1 = *(const float4*)(p + 4);
  float vv[8] = {v0.x, v0.y, v0.z, v0.w, v1.x, v1.y, v1.z, v1.w};
  u16 hi[8], lo[8];
#pragma unroll
  for (int i = 0; i < 8; ++i) {
    hi[i] = bf16_rn(vv[i]);
    lo[i] = bf16_rn(vv[i] - bf16_f(hi[i]));
  }
  u16x8 c0, c1;
#pragma unroll
  for (int i = 0; i < 4; ++i) {
    c0[2 * i] = hi[i];     c0[2 * i + 1] = lo[i];
    c1[2 * i] = hi[4 + i]; c1[2 * i + 1] = lo[4 + i];
  }
  int seg = kc >> 5;
  int ch0 = (kc >> 2) & 7;
  size_t base = (size_t)r * 2048 + seg * 64;
  *(u16x8*)&dst[base + (size_t)((ch0 ^ (r & 7)) << 3)] = c0;
  *(u16x8*)&dst[base + (size_t)(((ch0 | 1) ^ (r & 7)) << 3)] = c1;
}

// --------------- fp32 tiled GEMM (c0 init, optional dual store) ------------
template<int BM, int BN, int BK, int TM, int TN>
__launch_bounds__(256)
__global__ void gemm_nt(
    const float* __restrict__ A, const int* __restrict__ Aidx, int lda,
    const float* __restrict__ W, int ldw, int koff,
    const float* __restrict__ bias, float* __restrict__ C, float* __restrict__ C2,
    int ldc, int M, int N, int K) {
  constexpr int TX = BN / TN;
  constexpr int TY = BM / TM;
  static_assert(TX * TY == 256, "thread geometry");
  __shared__ float As[BK][BM + 4];
  __shared__ float Ws[BK][BN + 4];
  const int tid = threadIdx.x;
  const int tx = tid % TX, ty = tid / TX;
  const int m0 = blockIdx.y * BM, n0 = blockIdx.x * BN;
  float acc[TM][TN];
#pragma unroll
  for (int i = 0; i < TM; ++i)
#pragma unroll
    for (int j = 0; j < TN; ++j) acc[i][j] = 0.f;
  constexpr int AV = (BM * BK) / 4;
  constexpr int WV = (BN * BK) / 4;
  constexpr int KV = BK / 4;
  for (int k0 = 0; k0 < K; k0 += BK) {
#pragma unroll
    for (int lp = 0; lp < (AV + 255) / 256; ++lp) {
      int e = tid + lp * 256;
      if (e < AV) {
        int r = e / KV, kq = e % KV;
        int m = m0 + r;
        float4 v = make_float4(0.f, 0.f, 0.f, 0.f);
        if (m < M) {
          int row = Aidx ? Aidx[m] : m;
          v = *(const float4*)&A[(size_t)row * lda + k0 + kq * 4];
        }
        As[kq * 4 + 0][r] = v.x; As[kq * 4 + 1][r] = v.y;
        As[kq * 4 + 2][r] = v.z; As[kq * 4 + 3][r] = v.w;
      }
    }
#pragma unroll
    for (int lp = 0; lp < (WV + 255) / 256; ++lp) {
      int e = tid + lp * 256;
      if (e < WV) {
        int cc = e / KV, kq = e % KV;
        int n = n0 + cc;
        float4 v = make_float4(0.f, 0.f, 0.f, 0.f);
        if (n < N)
          v = *(const float4*)&W[(size_t)n * ldw + koff + k0 + kq * 4];
        Ws[kq * 4 + 0][cc] = v.x; Ws[kq * 4 + 1][cc] = v.y;
        Ws[kq * 4 + 2][cc] = v.z; Ws[kq * 4 + 3][cc] = v.w;
      }
    }
    __syncthreads();
#pragma unroll
    for (int kk = 0; kk < BK; ++kk) {
      float a[TM], b[TN];
#pragma unroll
      for (int i = 0; i < TM; ++i) a[i] = As[kk][ty * TM + i];
#pragma unroll
      for (int j = 0; j < TN; ++j) b[j] = Ws[kk][tx * TN + j];
#pragma unroll
      for (int i = 0; i < TM; ++i)
#pragma unroll
        for (int j = 0; j < TN; ++j)
          acc[i][j] += a[i] * b[j];
    }
    __syncthreads();
  }
#pragma unroll
  for (int i = 0; i < TM; ++i) {
    int m = m0 + ty * TM + i;
    if (m >= M) continue;
#pragma unroll
    for (int j = 0; j < TN; ++j) {
      int n = n0 + tx * TN + j;
      if (n >= N) continue;
      float v = acc[i][j];
      if (bias) v += bias[n];
      C[(size_t)m * ldc + n] = v;
      if (C2) C2[(size_t)m * ldc + n] = v;
    }
  }
}

// --------- pure-bf16 MFMA GEMM (round-11 single-buffered, proven) ----------
__launch_bounds__(256)
__global__ void gemm_bt(const u16* __restrict__ A, int Mrows,
                        const u16* __restrict__ Wb,
                        const float* __restrict__ bias,
                        const float* __restrict__ Dadd, int ldd, int dmask,
                        float* __restrict__ C, int ldc, int N, int nbx,
                        int mt, int ord) {
  __shared__ u16 lsA[128 * 64];
  __shared__ u16 lsB[128 * 64];

  int nwg = gridDim.x, bid = blockIdx.x;
  int q = nwg >> 3, r = nwg & 7;
  int xcd = bid & 7, base = bid >> 3;
  int wg = (xcd < r ? xcd * (q + 1) : r * (q + 1) + (xcd - r) * q) + base;
  int bx, by;
  if (ord) { by = wg % mt; bx = wg / mt; } else { bx = wg % nbx; by = wg / nbx; }
  const int m0 = by * 128, n0 = bx * 128;

  const int tid = threadIdx.x, w = tid >> 6, l = tid & 63;
  const int lr = l & 15, lq = l >> 4;
  const int wm = (w >> 1) * 64, wn = (w & 1) * 64;

  f32x4 acc[4][4] = {};

  for (int kt = 0; kt < 32; ++kt) {
#pragma unroll
    for (int i = 0; i < 4; ++i) {
      int rb = w * 32 + i * 8;
      int gm = m0 + rb + (l >> 3);
      if (gm > Mrows - 1) gm = Mrows - 1;
      const u16* ga = A + (size_t)gm * 2048 + kt * 64 + (l & 7) * 8;
      __builtin_amdgcn_global_load_lds(
          (const __attribute__((address_space(1))) void*)ga,
          (__attribute__((address_space(3))) void*)(lsA + rb * 64), 16, 0, 0);
      const u16* gb = Wb + (size_t)(n0 + rb + (l >> 3)) * 2048 + kt * 64 + (l & 7) * 8;
      __builtin_amdgcn_global_load_lds(
          (const __attribute__((address_space(1))) void*)gb,
          (__attribute__((address_space(3))) void*)(lsB + rb * 64), 16, 0, 0);
    }
    asm volatile("s_waitcnt vmcnt(0)" ::: "memory");
    __syncthreads();

    bf16x8 af[4][2], bfr[4][2];
#pragma unroll
    for (int i = 0; i < 4; ++i) {
      int ar = wm + i * 16 + lr;
#pragma unroll
      for (int s = 0; s < 2; ++s)
        af[i][s] = *(const bf16x8*)&lsA[ar * 64 + (((s << 2) + lq) ^ (ar & 7)) * 8];
    }
#pragma unroll
    for (int j = 0; j < 4; ++j) {
      int br = wn + j * 16 + lr;
#pragma unroll
      for (int s = 0; s < 2; ++s)
        bfr[j][s] = *(const bf16x8*)&lsB[br * 64 + (((s << 2) + lq) ^ (br & 7)) * 8];
    }
#pragma unroll
    for (int i = 0; i < 4; ++i)
#pragma unroll
      for (int j = 0; j < 4; ++j) {
        acc[i][j] = __builtin_amdgcn_mfma_f32_16x16x32_bf16(af[i][0], bfr[j][0], acc[i][j], 0, 0, 0);
        acc[i][j] = __builtin_amdgcn_mfma_f32_16x16x32_bf16(af[i][1], bfr[j][1], acc[i][j], 0, 0, 0);
      }
    __syncthreads();
  }

#pragma unroll
  for (int i = 0; i < 4; ++i) {
    int mbase = m0 + wm + i * 16 + lq * 4;
#pragma unroll
    for (int j = 0; j < 4; ++j) {
      int n = n0 + wn + j * 16 + lr;
      float badd = bias ? bias[n] : 0.f;
#pragma unroll
      for (int rr = 0; rr < 4; ++rr) {
        int m = mbase + rr;
        if (m >= Mrows) continue;
        float v = acc[i][j][rr] + badd;
        if (Dadd) {
          int dr = (dmask < 0) ? m : (m & dmask);
          v += Dadd[(size_t)dr * ldd + n];
        }
        C[(size_t)m * ldc + n] = v;
      }
    }
  }
}

// ----------- split-bf16 MFMA GEMM on f32 inputs (tier2/3 decoder) ----------
__launch_bounds__(256)
__global__ void gemm_sp(
    const float* __restrict__ A, int lda,
    const float* __restrict__ W, int ldw,
    const float* __restrict__ bias,
    float* __restrict__ C, int ldc, int M, int N, int K, int nbx) {
  __shared__ u16 As_h[128][40], As_l[128][40];
  __shared__ u16 Ws_h[128][40], Ws_l[128][40];
  int nwg = gridDim.x, bid = blockIdx.x;
  int q = nwg >> 3, r = nwg & 7;
  int xcd = bid & 7, base = bid >> 3;
  int wg = (xcd < r ? xcd * (q + 1) : r * (q + 1) + (xcd - r) * q) + base;
  int bx = wg % nbx, by = wg / nbx;
  const int m0 = by * 128, n0 = bx * 128;
  const int tid = threadIdx.x;
  const int wave = tid >> 6, lane = tid & 63;
  const int lr = lane & 15, lq = lane >> 4;
  const int wm = (wave >> 1) * 64, wn = (wave & 1) * 64;
  f32x4 acc[4][4] = {};
  for (int k0 = 0; k0 < K; k0 += 32) {
#pragma unroll
    for (int lp = 0; lp < 4; ++lp) {
      int s = tid + lp * 256;
      int row = s >> 3, kq = s & 7;
      float4 v = make_float4(0.f, 0.f, 0.f, 0.f);
      int gm = m0 + row;
      if (gm < M)
        v = *(const float4*)&A[(size_t)gm * lda + k0 + kq * 4];
      u16 h0 = bf16_rn(v.x), h1 = bf16_rn(v.y), h2 = bf16_rn(v.z), h3 = bf16_rn(v.w);
      u16 l0 = bf16_rn(v.x - bf16_f(h0)), l1 = bf16_rn(v.y - bf16_f(h1));
      u16 l2 = bf16_rn(v.z - bf16_f(h2)), l3 = bf16_rn(v.w - bf16_f(h3));
      *(uint2*)&As_h[row][kq * 4] =
          make_uint2((u32)h0 | ((u32)h1 << 16), (u32)h2 | ((u32)h3 << 16));
      *(uint2*)&As_l[row][kq * 4] =
          make_uint2((u32)l0 | ((u32)l1 << 16), (u32)l2 | ((u32)l3 << 16));
    }
#pragma unroll
    for (int lp = 0; lp < 4; ++lp) {
      int s = tid + lp * 256;
      int col = s >> 3, kq = s & 7;
      int n = n0 + col;
      float4 v = make_float4(0.f, 0.f, 0.f, 0.f);
      if (n < N)
        v = *(const float4*)&W[(size_t)n * ldw + k0 + kq * 4];
      u16 h0 = bf16_rn(v.x), h1 = bf16_rn(v.y), h2 = bf16_rn(v.z), h3 = bf16_rn(v.w);
      u16 l0 = bf16_rn(v.x - bf16_f(h0)), l1 = bf16_rn(v.y - bf16_f(h1));
      u16 l2 = bf16_rn(v.z - bf16_f(h2)), l3 = bf16_rn(v.w - bf16_f(h3));
      *(uint2*)&Ws_h[col][kq * 4] =
          make_uint2((u32)h0 | ((u32)h1 << 16), (u32)h2 | ((u32)h3 << 16));
      *(uint2*)&Ws_l[col][kq * 4] =
          make_uint2((u32)l0 | ((u32)l1 << 16), (u32)l2 | ((u32)l3 << 16));
    }
    __syncthreads();
    bf16x8 ah[4], al[4], bh[4], bl[4];
#pragma unroll
    for (int i = 0; i < 4; ++i) {
      ah[i] = *(const bf16x8*)&As_h[wm + i * 16 + lr][lq * 8];
      al[i] = *(const bf16x8*)&As_l[wm + i * 16 + lr][lq * 8];
    }
#pragma unroll
    for (int j = 0; j < 4; ++j) {
      bh[j] = *(const bf16x8*)&Ws_h[wn + j * 16 + lr][lq * 8];
      bl[j] = *(const bf16x8*)&Ws_l[wn + j * 16 + lr][lq * 8];
    }
#pragma unroll
    for (int i = 0; i < 4; ++i)
#pragma unroll
      for (int j = 0; j < 4; ++j) {
        acc[i][j] = __builtin_amdgcn_mfma_f32_16x16x32_bf16(ah[i], bh[j], acc[i][j], 0, 0, 0);
        acc[i][j] = __builtin_amdgcn_mfma_f32_16x16x32_bf16(ah[i], bl[j], acc[i][j], 0, 0, 0);
        acc[i][j] = __builtin_amdgcn_mfma_f32_16x16x32_bf16(al[i], bh[j], acc[i][j], 0, 0, 0);
      }
    __syncthreads();
  }
#pragma unroll
  for (int i = 0; i < 4; ++i) {
    int mbase = m0 + wm + i * 16 + lq * 4;
#pragma unroll
    for (int j = 0; j < 4; ++j) {
      int n = n0 + wn + j * 16 + lr;
      if (n >= N) continue;
      float badd = bias ? bias[n] : 0.f;
#pragma unroll
      for (int rr = 0; rr < 4; ++rr) {
        int m = mbase + rr;
        if (m >= M) continue;
        C[(size_t)m * ldc + n] = acc[i][j][rr] + badd;
      }
    }
  }
}

// ---------------- helpers for fused recurrence -----------------------------
__device__ __forceinline__ void gemm_half(
    const u32* __restrict__ hp, int rg, int w, int lr, int lq,
    const bf16x8 (&bfr)[8][4], f32x4 (&acc)[2][4]) {
  bf16x8 af[8][2];
#pragma unroll
  for (int s = 0; s < 8; ++s)
#pragma unroll
    for (int mt = 0; mt < 2; ++mt) {
      int m = rg * 32 + mt * 16 + lr;
      int seg = w * 4 + (s >> 1);
      int cis = ((((s & 1) << 2) + lq) ^ (lr & 7));
      const u32* p = hp + (size_t)m * 1024 + seg * 32 + cis * 4;
      asm volatile("global_load_dwordx4 %0, %1, off sc0 sc1"
                   : "=v"(af[s][mt]) : "v"(p) : "memory");
    }
  asm volatile("s_waitcnt vmcnt(0)" ::: "memory");
  __builtin_amdgcn_sched_barrier(0);
#pragma unroll
  for (int s = 0; s < 8; ++s)
#pragma unroll
    for (int mt = 0; mt < 2; ++mt)
#pragma unroll
      for (int nt = 0; nt < 4; ++nt)
        acc[mt][nt] = __builtin_amdgcn_mfma_f32_16x16x32_bf16(
            af[s][mt], bfr[s][nt], acc[mt][nt], 0, 0, 0);
}

// per-wave poll: wave w needs only writers ct in [8w, 8w+8) of its rg.
__device__ __forceinline__ void poll_src(const u32* flags, int rg, int w, int l, u32 tgt) {
  int guard = 0;
  for (;;) {
    u32 v = tgt;
    if (l < 8)
      v = __hip_atomic_load(flags + (size_t)((rg << 6) + (w << 3) + l) * 4,
                            __ATOMIC_RELAXED, __HIP_MEMORY_SCOPE_AGENT);
    if (__all(v >= tgt)) break;
    if (++guard > (1 << 23)) break;
    __builtin_amdgcn_s_sleep(1);
  }
}

// 64-flag poll (decoder): all ct of one rg.
__device__ __forceinline__ void poll_flags(const u32* flags, int rg, int l, u32 tgt) {
  int guard = 0;
  for (;;) {
    u32 v = __hip_atomic_load(flags + (size_t)((rg << 6) + l) * 4,
                              __ATOMIC_RELAXED, __HIP_MEMORY_SCOPE_AGENT);
    if (__all(v >= tgt)) break;
    if (++guard > (1 << 23)) break;
    __builtin_amdgcn_s_sleep(1);
  }
}

// concurrent decoder block: cols [dblk*128,+128), 25 chunks of 2 timesteps.
// 8 waves, acc[2][4] (32 VGPR). LDS: As[128][64] + Bs[128][64] u16 (32KB).
__device__ void decoder_block(char* smem, int dblk,
                              const u32* __restrict__ h1s,
                              const float* __restrict__ decW,
                              const float* __restrict__ dec_b,
                              const u32* __restrict__ flg1,
                              float* __restrict__ outC, int tid) {
  u16* As = (u16*)smem;
  u16* Bs = (u16*)(smem + 32768);
  const int w = tid >> 6, l = tid & 63;
  const int lr = l & 15, lq = l >> 4;
  const int n0 = dblk * 128;
  const u16* h1u = (const u16*)h1s;
  const int wr = w >> 1, wc = w & 1;   // wave tile: rows wr*32..+32, cols wc*64..+64

  for (int ch = 0; ch < 25; ++ch) {
    const u32 tgt = (u32)(2 * ch + 2);
    if (w == 0) { poll_flags(flg1, 0, l, tgt); poll_flags(flg1, 1, l, tgt); }
    __syncthreads();

    f32x4 acc[2][4] = {};
    for (int kt = 0; kt < 32; ++kt) {
      // stage A: 128 rows (slots 2ch+1, 2ch+2), 2 wave-gloads/wave
#pragma unroll
      for (int i = 0; i < 2; ++i) {
        int rb = w * 16 + i * 8;
        int grow = rb + (l >> 3);
        int slot = 2 * ch + 1 + (grow >> 6);
        const u16* ga = h1u + (size_t)slot * (64 * 2048) +
                        (size_t)(grow & 63) * 2048 + kt * 64 + (l & 7) * 8;
        __builtin_amdgcn_global_load_lds(
            (const __attribute__((address_space(1))) void*)ga,
            (__attribute__((address_space(3))) void*)(As + rb * 64), 16, 0, 0);
      }
      // stage B: dec_W f32 -> hi|lo interleaved (chunk-XOR); 1 row-seg/thread
      {
        int row = tid >> 2, kq8 = (tid & 3) * 8;
        const float* p = decW + (size_t)(n0 + row) * 1024 + kt * 32 + kq8;
        float4 v0 = *(const float4*)p, v1 = *(const float4*)(p + 4);
        float vv[8] = {v0.x, v0.y, v0.z, v0.w, v1.x, v1.y, v1.z, v1.w};
        u16 hi[8], lo[8];
#pragma unroll
        for (int q2 = 0; q2 < 8; ++q2) {
          hi[q2] = bf16_rn(vv[q2]);
          lo[q2] = bf16_rn(vv[q2] - bf16_f(hi[q2]));
        }
        u16x8 c0, c1;
#pragma unroll
        for (int q2 = 0; q2 < 4; ++q2) {
          c0[2 * q2] = hi[q2];     c0[2 * q2 + 1] = lo[q2];
          c1[2 * q2] = hi[4 + q2]; c1[2 * q2 + 1] = lo[4 + q2];
        }
        int c0i = kq8 >> 2;                 // 0,2,4,6
        u16* dst = Bs + row * 64;
        *(u16x8*)&dst[(c0i ^ (row & 7)) << 3] = c0;
        *(u16x8*)&dst[((c0i | 1) ^ (row & 7)) << 3] = c1;
      }
      asm volatile("s_waitcnt vmcnt(0)" ::: "memory");
      __syncthreads();

      bf16x8 af[2][2], bfr[2][4];
#pragma unroll
      for (int mt = 0; mt < 2; ++mt) {
        int ar = wr * 32 + mt * 16 + lr;
#pragma unroll
        for (int s = 0; s < 2; ++s)
          af[mt][s] = *(const bf16x8*)&As[ar * 64 + (((s << 2) + lq) ^ (ar & 7)) * 8];
      }
#pragma unroll
      for (int nt = 0; nt < 4; ++nt) {
        int br = wc * 64 + nt * 16 + lr;
#pragma unroll
        for (int s = 0; s < 2; ++s)
          bfr[s][nt] = *(const bf16x8*)&Bs[br * 64 + (((s << 2) + lq) ^ (br & 7)) * 8];
      }
#pragma unroll
      for (int s = 0; s < 2; ++s)
#pragma unroll
        for (int mt = 0; mt < 2; ++mt)
#pragma unroll
          for (int nt = 0; nt < 4; ++nt)
            acc[mt][nt] = __builtin_amdgcn_mfma_f32_16x16x32_bf16(
                af[mt][s], bfr[s][nt], acc[mt][nt], 0, 0, 0);
      __syncthreads();
    }
    // epilogue
#pragma unroll
    for (int mt = 0; mt < 2; ++mt) {
      int mrow0 = wr * 32 + mt * 16 + lq * 4;
#pragma unroll
      for (int nt = 0; nt < 4; ++nt) {
        int col = n0 + wc * 64 + nt * 16 + lr;
        float badd = dec_b[col];
#pragma unroll
        for (int rr = 0; rr < 4; ++rr)
          outC[(size_t)(ch * 128 + mrow0 + rr) * V_ + col] = acc[mt][nt][rr] + badd;
      }
    }
  }
}

// ------ fused dual-layer persistent recurrence (+ concurrent decoder) ------
template<bool DUAL, bool EMIT, bool DEC>
__launch_bounds__(512, 1)
__global__ void rnn_dual(const u16* __restrict__ Whh0b, const u16* __restrict__ Whh1b,
                         const u16* __restrict__ Wih1b,
                         const float* __restrict__ xg0all, const float* __restrict__ bias1p,
                         float* __restrict__ cL0, float* __restrict__ hL0,
                         float* __restrict__ cL1, float* __restrict__ hL1,
                         u32* __restrict__ h0s, u32* __restrict__ h1s,
                         float* __restrict__ hsf,
                         u32* __restrict__ flg0, u32* __restrict__ flg1,
                         const float* __restrict__ decW, const float* __restrict__ dec_b,
                         float* __restrict__ outC, int T) {
  __shared__ char smem[69632];
  float* partial = (float*)smem;   // rnn: [8][32][68] f32

  const int bid = blockIdx.x;
  const int tid = threadIdx.x, w = tid >> 6, l = tid & 63;
  const int lr = l & 15, lq = l >> 4;

  if (DEC && bid >= 256) {
    decoder_block(smem, bid - 256, h1s, decW, dec_b, flg1, outC, tid);
    return;
  }

  const int x = bid & 7, j = bid >> 3;
  const int layer = DUAL ? (j & 1) : 0;
  const int idx = DUAL ? (j >> 1) : j;
  const int ct = x * 8 + (idx & 7);
  const int rg = idx >> 3;

  // ---- recurrent-W fragments (cached loads; L2-resident per XCD)
  const u16* WbA = (layer ? Whh1b : Whh0b) + (size_t)(ct * 64) * 2048;
  bf16x8 bfragA[8][4];
#pragma unroll
  for (int s = 0; s < 8; ++s)
#pragma unroll
    for (int nt = 0; nt < 4; ++nt) {
      int row = nt * 16 + lr;
      int seg = w * 4 + (s >> 1);
      int cis = ((((s & 1) << 2) + lq) ^ (lr & 7));
      bfragA[s][nt] = *(const bf16x8*)&WbA[(size_t)row * 2048 + seg * 64 + cis * 8];
    }
  bf16x8 bfragX[8][4];
  if (DUAL && layer) {
    const u16* WbX = Wih1b + (size_t)(ct * 64) * 2048;
#pragma unroll
    for (int s = 0; s < 8; ++s)
#pragma unroll
      for (int nt = 0; nt < 4; ++nt) {
        int row = nt * 16 + lr;
        int seg = w * 4 + (s >> 1);
        int cis = ((((s & 1) << 2) + lq) ^ (lr & 7));
        bfragX[s][nt] = *(const bf16x8*)&WbX[(size_t)row * 2048 + seg * 64 + cis * 8];
      }
  }

  const int cm = tid >> 4, cu = tid & 15;
  const int m_c = rg * 32 + cm;
  const int unit = ct * 16 + cu;
  float* cL = layer ? cL1 : cL0;
  float* hL = layer ? hL1 : hL0;
  u32* hsl = layer ? h1s : h0s;
  u32* flgS = layer ? flg1 : flg0;
  float creg = cL[m_c * H_ + unit];
  float bset[4];
  if (layer) {
#pragma unroll
    for (int g = 0; g < 4; ++g)
      bset[g] = bias1p[ct * 64 + g * 16 + cu];
  }

  for (int t = 0; t < T; ++t) {
    float xgv[4];
    if (!layer) {
      const float* xg = xg0all + (size_t)t * ((size_t)B_ * G_);
#pragma unroll
      for (int g = 0; g < 4; ++g)
        xgv[g] = xg[(size_t)m_c * G_ + ct * 64 + g * 16 + cu];
    } else {
#pragma unroll
      for (int g = 0; g < 4; ++g) xgv[g] = bset[g];
    }

    f32x4 acc[2][4] = {};

    if (layer) {
      if (t) poll_src(flg1, rg, w, l, (u32)t);
      gemm_half(h1s + (size_t)t * (B_ * 1024), rg, w, lr, lq, bfragA, acc);
      poll_src(flg0, rg, w, l, (u32)(t + 1));
      gemm_half(h0s + (size_t)(t + 1) * (B_ * 1024), rg, w, lr, lq, bfragX, acc);
    } else {
      if (t) poll_src(flg0, rg, w, l, (u32)t);
      gemm_half(h0s + (size_t)t * (B_ * 1024), rg, w, lr, lq, bfragA, acc);
    }

    // K-split reduction through LDS
#pragma unroll
    for (int mt = 0; mt < 2; ++mt)
#pragma unroll
      for (int nt = 0; nt < 4; ++nt)
#pragma unroll
        for (int rr = 0; rr < 4; ++rr)
          partial[(w * 32 + mt * 16 + lq * 4 + rr) * 68 + nt * 16 + lr] = acc[mt][nt][rr];
    __syncthreads();

    // cell
    float g4[4];
#pragma unroll
    for (int g = 0; g < 4; ++g) {
      float ssum = xgv[g];
#pragma unroll
      for (int p = 0; p < 8; ++p) ssum += partial[(p * 32 + cm) * 68 + g * 16 + cu];
      g4[g] = ssum;
    }
    float cn = sigm(g4[1]) * creg + sigm(g4[0]) * tanhf(g4[2]);
    float hn = sigm(g4[3]) * tanhf(cn);
    creg = cn;
    if (EMIT && layer) hsf[(size_t)t * (B_ * H_) + m_c * H_ + unit] = hn;
    if (t == T - 1) { cL[m_c * H_ + unit] = cn; hL[m_c * H_ + unit] = hn; }
    u16 hh = bf16_rn(hn);
    u16 hl2 = bf16_rn(hn - bf16_f(hh));
    u32 packed = (u32)hh | ((u32)hl2 << 16);
    u32* hnext = hsl + (size_t)(t + 1) * (B_ * 1024);
    u32 hidx = m_c * 1024 + ((unit >> 5) << 5) +
               ((((unit >> 2) & 7) ^ (m_c & 7)) << 2) + (unit & 3);
    {
      u32* sp = hnext + hidx;
      asm volatile("global_store_dword %0, %1, off sc0 sc1"
                   :: "v"(sp), "v"(packed) : "memory");
    }

    // publish (unconditional: decoder needs flg1 = T)
    asm volatile("s_waitcnt vmcnt(0)" ::: "memory");
    __syncthreads();
    if (tid == 0)
      __hip_atomic_store(flgS + (size_t)((rg << 6) + ct) * 4, (u32)(t + 1),
                         __ATOMIC_RELAXED, __HIP_MEMORY_SCOPE_AGENT);
  }
}

// --------- single-step kernel (tiny-ws fallback), perm_g cell --------------
__launch_bounds__(256)
__global__ void rnn_step(const u16* __restrict__ hprev, const u16* __restrict__ Wb,
                         const float* __restrict__ xg,
                         float* __restrict__ c, float* __restrict__ hf,
                         u32* __restrict__ hout) {
  __shared__ char smem[32768];
  u16* lsA = (u16*)smem;
  u16* lsB = (u16*)(smem + 16384);
  const int nt = blockIdx.x, n0 = nt * 64;
  const int tid = threadIdx.x, w = tid >> 6, l = tid & 63;
  const int lr = l & 15, lq = l >> 4;
  f32x4 acc[4] = {};
  for (int kt = 0; kt < 16; ++kt) {
#pragma unroll
    for (int i = 0; i < 4; ++i) {
      int rb = w * 16 + i * 4;
      const u16* ga = hprev + (size_t)(rb + (l >> 4)) * 2048 + kt * 128 + (l & 15) * 8;
      __builtin_amdgcn_global_load_lds(
          (const __attribute__((address_space(1))) void*)ga,
          (__attribute__((address_space(3))) void*)(lsA + rb * 128), 16, 0, 0);
      const u16* gb = Wb + (size_t)(n0 + rb + (l >> 4)) * 2048 + kt * 128 + (l & 15) * 8;
      __builtin_amdgcn_global_load_lds(
          (const __attribute__((address_space(1))) void*)gb,
          (__attribute__((address_space(3))) void*)(lsB + rb * 128), 16, 0, 0);
    }
    asm volatile("s_waitcnt vmcnt(0)" ::: "memory");
    __syncthreads();
    bf16x8 af[4];
    int ar = w * 16 + lr;
#pragma unroll
    for (int s = 0; s < 4; ++s)
      af[s] = *(const bf16x8*)&lsA[ar * 128 + (s >> 1) * 64 + ((((s & 1) << 2) + lq) ^ (ar & 7)) * 8];
#pragma unroll
    for (int jj = 0; jj < 4; ++jj) {
      int br = jj * 16 + lr;
#pragma unroll
      for (int s = 0; s < 4; ++s) {
        bf16x8 bv = *(const bf16x8*)&lsB[br * 128 + (s >> 1) * 64 + ((((s & 1) << 2) + lq) ^ (br & 7)) * 8];
        acc[jj] = __builtin_amdgcn_mfma_f32_16x16x32_bf16(af[s], bv, acc[jj], 0, 0, 0);
      }
    }
    __syncthreads();
  }
  float* gsh = (float*)smem;
#pragma unroll
  for (int jj = 0; jj < 4; ++jj)
#pragma unroll
    for (int rr = 0; rr < 4; ++rr)
      gsh[(w * 16 + lq * 4 + rr) * 68 + jj * 16 + lr] = acc[jj][rr];
  __syncthreads();
  const int ui = tid & 15, mq = tid >> 4;
#pragma unroll
  for (int mr = 0; mr < 4; ++mr) {
    int m = mr * 16 + mq;
    float gi = gsh[m * 68 + 0 + ui]  + xg[(size_t)m * G_ + n0 + 0 + ui];
    float gf = gsh[m * 68 + 16 + ui] + xg[(size_t)m * G_ + n0 + 16 + ui];
    float gg = gsh[m * 68 + 32 + ui] + xg[(size_t)m * G_ + n0 + 32 + ui];
    float go = gsh[m * 68 + 48 + ui] + xg[(size_t)m * G_ + n0 + 48 + ui];
    int unit = nt * 16 + ui;
    int ci = m * H_ + unit;
    float cn = sigm(gf) * c[ci] + sigm(gi) * tanhf(gg);
    float hn = sigm(go) * tanhf(cn);
    c[ci] = cn;
    hf[ci] = hn;
    u16 hh = bf16_rn(hn);
    u16 hl = bf16_rn(hn - bf16_f(hh));
    u32 hidx = m * 1024 + ((unit >> 5) << 5) +
               ((((unit >> 2) & 7) ^ (m & 7)) << 2) + (unit & 3);
    hout[hidx] = (u32)hh | ((u32)hl << 16);
  }
}

// ---------------------------------------------------------------------------
extern "C" void kernel_launch(void* const* d_in, const int* in_sizes, int n_in,
                              void* d_out, int out_size, void* d_ws, size_t ws_size,
                              hipStream_t stream) {
  const int*   word  = (const int*)  d_in[0];
  const int*   seq   = (const int*)  d_in[1];
  const float* emb   = (const float*)d_in[2];
  const float* w2h_W = (const float*)d_in[3];
  const float* w2h_b = (const float*)d_in[4];
  const float* W_ih0 = (const float*)d_in[5];
  const float* W_hh0 = (const float*)d_in[6];
  const float* b_ih0 = (const float*)d_in[7];
  const float* b_hh0 = (const float*)d_in[8];
  const float* W_ih1 = (const float*)d_in[9];
  const float* W_hh1 = (const float*)d_in[10];
  const float* b_ih1 = (const float*)d_in[11];
  const float* b_hh1 = (const float*)d_in[12];
  const float* dec_W = (const float*)d_in[13];
  const float* dec_b = (const float*)d_in[14];

  float* out = (float*)d_out;
  float* hL0 = out + 102400000;
  float* hL1 = hL0 + B_ * H_;
  float* cL0 = out + 102531072;
  float* cL1 = cL0 + B_ * H_;

  // d_out scratch with PRE-RNN lifetime only (safe in tier0)
  u16*   x0w_bf   = (u16*)(out + 13200000);
  u16*   x0seq_bf = (u16*)(out + 13300000);
  u16*   wih0a_bf = (u16*)(out + 20000000);
  u16*   wih0b_bf = (u16*)(out + 24200000);
  float* y_w      = out + 73800000;
  float* bias0p   = out + 74400000;

  const size_t need0    = 129600000;               // tier0: concurrent decode
  const size_t need_hs1 = (size_t)T_ * B_ * H_ * 4;
  const bool tier0 = ws_size >= need0;
  const bool tier2 = !tier0 && ws_size >= need_hs1;

  if (tier0) {
    char* wsb = (char*)d_ws;
    u32*   h1p    = (u32*)wsb;                       // [51][64][1024]
    u32*   h0p    = (u32*)(wsb + 13369344);
    float* xg0p   = (float*)(wsb + 26738688);        // [3200][4096]
    u16*   whh0p  = (u16*)(wsb + 79167488);
    u16*   whh1p  = (u16*)(wsb + 95944704);
    u16*   wih1p  = (u16*)(wsb + 112721920);
    float* b1p    = (float*)(wsb + 129499136);
    u32*   f0p    = (u32*)(wsb + 129515520);
    u32*   f1p    = (u32*)(wsb + 129519616);

    fill_zero<<<8, 256, 0, stream>>>((float*)f0p, 2048);           // both flag sets
    fill_zero<<<256, 256, 0, stream>>>((float*)h0p, 65536);        // slot 0
    fill_zero<<<256, 256, 0, stream>>>((float*)h1p, 65536);
    bias_perm<<<16, 256, 0, stream>>>(b_ih0, b_hh0, bias0p);
    bias_perm<<<16, 256, 0, stream>>>(b_ih1, b_hh1, b1p);

    gemm_nt<64, 64, 16, 4, 4><<<dim3(16, 1), 256, 0, stream>>>(
        emb, word, E_, w2h_W, E_, 0, w2h_b, cL0, cL1, H_, B_, H_, E_);

    conv_w<<<2048, 256, 0, stream>>>(W_ih0, 2 * E_, 0,  nullptr, 1, G_, wih0a_bf);
    conv_w<<<2048, 256, 0, stream>>>(W_ih0, 2 * E_, E_, nullptr, 1, G_, wih0b_bf);
    conv_w<<<2048, 256, 0, stream>>>(W_ih1, H_, 0, nullptr, 1, G_, wih1p);
    conv_w<<<2048, 256, 0, stream>>>(W_hh0, H_, 0, nullptr, 1, G_, whh0p);
    conv_w<<<2048, 256, 0, stream>>>(W_hh1, H_, 0, nullptr, 1, G_, whh1p);
    conv_w<<<32,   256, 0, stream>>>(emb, E_, 0, word, 0, B_, x0w_bf);
    conv_w<<<1600, 256, 0, stream>>>(emb, E_, 0, seq, 0, T_ * B_, x0seq_bf);

    gemm_bt<<<32, 256, 0, stream>>>(x0w_bf, B_, wih0a_bf, bias0p,
                                    nullptr, 0, -1, y_w, G_, G_, 32, 1, 0);
    gemm_bt<<<800, 256, 0, stream>>>(x0seq_bf, T_ * B_, wih0b_bf, nullptr,
                                     y_w, G_, 63, xg0p, G_, G_, 32, 25, 0);

    rnn_dual<true, false, true><<<506, 512, 0, stream>>>(
        whh0p, whh1p, wih1p, xg0p, b1p,
        cL0, hL0, cL1, hL1, h0p, h1p, nullptr, f0p, f1p,
        dec_W, dec_b, out, T_);
  } else {
    // legacy scratch layout in d_out (decoder runs AFTER recurrence)
    float* xg0      = out;
    u32*   hs0slots = (u32*)(out + 16600000);
    u16*   wih1_bf  = (u16*)(out + 28400000);
    u16*   whh0_bf  = (u16*)(out + 32600000);
    u16*   whh1_bf  = (u16*)(out + 36800000);
    float* bias1p   = out + 74410000;
    float* xg1      = out + 87560192;
    u32*   h1alt    = (u32*)(out + 91000000);
    u32*   flg0     = (u32*)(out + 101000000);
    u32*   flg1     = (u32*)(out + 101004096);
    u32*   hbfA     = (u32*)(out + 101100000);
    u32*   hbfB     = (u32*)(out + 101200000);
    float* hs1f     = (float*)d_ws;

    fill_zero<<<32, 256, 0, stream>>>(out + 101000000, 8192);
    fill_zero<<<256, 256, 0, stream>>>((float*)hs0slots, 65536);
    if (tier2) fill_zero<<<256, 256, 0, stream>>>((float*)h1alt, 65536);
    bias_perm<<<16, 256, 0, stream>>>(b_ih0, b_hh0, bias0p);
    bias_perm<<<16, 256, 0, stream>>>(b_ih1, b_hh1, bias1p);

    gemm_nt<64, 64, 16, 4, 4><<<dim3(16, 1), 256, 0, stream>>>(
        emb, word, E_, w2h_W, E_, 0, w2h_b, cL0, cL1, H_, B_, H_, E_);

    conv_w<<<2048, 256, 0, stream>>>(W_ih0, 2 * E_, 0,  nullptr, 1, G_, wih0a_bf);
    conv_w<<<2048, 256, 0, stream>>>(W_ih0, 2 * E_, E_, nullptr, 1, G_, wih0b_bf);
    conv_w<<<2048, 256, 0, stream>>>(W_ih1, H_, 0, nullptr, 1, G_, wih1_bf);
    conv_w<<<2048, 256, 0, stream>>>(W_hh0, H_, 0, nullptr, 1, G_, whh0_bf);
    conv_w<<<2048, 256, 0, stream>>>(W_hh1, H_, 0, nullptr, 1, G_, whh1_bf);
    conv_w<<<32,   256, 0, stream>>>(emb, E_, 0, word, 0, B_, x0w_bf);
    conv_w<<<1600, 256, 0, stream>>>(emb, E_, 0, seq, 0, T_ * B_, x0seq_bf);

    gemm_bt<<<32, 256, 0, stream>>>(x0w_bf, B_, wih0a_bf, bias0p,
                                    nullptr, 0, -1, y_w, G_, G_, 32, 1, 0);
    gemm_bt<<<800, 256, 0, stream>>>(x0seq_bf, T_ * B_, wih0b_bf, nullptr,
                                     y_w, G_, 63, xg0, G_, G_, 32, 25, 0);

    if (tier2) {
      rnn_dual<true, true, false><<<256, 512, 0, stream>>>(
          whh0_bf, whh1_bf, wih1_bf, xg0, bias1p,
          cL0, hL0, cL1, hL1, hs0slots, h1alt, hs1f, flg0, flg1,
          nullptr, nullptr, nullptr, T_);
      gemm_sp<<<6250, 256, 0, stream>>>(
          hs1f, H_, dec_W, H_, dec_b, out, V_, T_ * B_, V_, H_, 250);
    } else {
      rnn_dual<false, false, false><<<128, 512, 0, stream>>>(
          whh0_bf, whh1_bf, wih1_bf, xg0, bias1p,
          cL0, hL0, cL1, hL1, hs0slots, nullptr, nullptr, flg0, flg1,
          nullptr, nullptr, nullptr, T_);
      gemm_bt<<<800, 256, 0, stream>>>((const u16*)(hs0slots + (size_t)B_ * 1024),
                                       T_ * B_, wih1_bf, bias1p,
                                       nullptr, 0, -1, xg1, G_, G_, 32, 25, 0);
      for (int t = 0; t < T_; ++t) {
        const u16* hp = t ? (const u16*)((t & 1) ? hbfA : hbfB) : (const u16*)hs0slots;
        u32* ho = (t & 1) ? hbfB : hbfA;
        rnn_step<<<64, 256, 0, stream>>>(
            hp, whh1_bf, xg1 + (size_t)t * B_ * G_, cL1, hL1, ho);
        gemm_sp<<<250, 256, 0, stream>>>(
            hL1, H_, dec_W, H_, dec_b, out + (size_t)t * B_ * V_, V_, B_, V_, H_, 250);
      }
    }
  }
}

// Round 17
// 1770.289 us; speedup vs baseline: 1.2780x; 1.2780x over previous
//
#include <hip/hip_runtime.h>
#include <cstddef>

// ---------------------------------------------------------------------------
// RNNModel round 17 (= round-15 restore, best measured 1770us).
// Round-11 single-buffered gemm_bt decoder (616us) + per-wave-poll dual-layer
// persistent recurrence (834us) + dual-store c0 init.
// h exchange: inline-asm sc0/sc1 bypass loads/stores. Flags: relaxed agent
// atomics, 16B stride. h packed u32 (hi|lo bf16), virtual-K interleave.
// Gate perm_g: col n <-> W row ((n>>4)&3)*1024+(n>>6)*16+(n&15).
// Chunk perm: 16B chunk c in each 128B segment stored at c^(row&7).
// ---------------------------------------------------------------------------

static constexpr int T_ = 50, B_ = 64, E_ = 1024, H_ = 1024, V_ = 32000;
static constexpr int G_ = 4096;

typedef unsigned short u16;
typedef unsigned int u32;
typedef unsigned long long u64;
typedef __attribute__((ext_vector_type(8))) short bf16x8;
typedef __attribute__((ext_vector_type(8))) unsigned short u16x8;
typedef __attribute__((ext_vector_type(4))) float f32x4;

__device__ __forceinline__ int perm_g(int n) {
  return ((n >> 4) & 3) * H_ + (n >> 6) * 16 + (n & 15);
}
__device__ __forceinline__ u16 bf16_rn(float x) {
  union { float f; unsigned u; } a; a.f = x;
  unsigned r = a.u + 0x7fffu + ((a.u >> 16) & 1u);
  return (u16)(r >> 16);
}
__device__ __forceinline__ float bf16_f(u16 h) {
  union { float f; unsigned u; } a; a.u = ((unsigned)h) << 16;
  return a.f;
}
__device__ __forceinline__ float sigm(float x) { return 1.f / (1.f + __expf(-x)); }

__global__ void fill_zero(float* p, int n) {
  int i = blockIdx.x * blockDim.x + threadIdx.x;
  if (i < n) p[i] = 0.f;
}
__global__ void bias_perm(const float* a, const float* b, float* dst) {
  int n = blockIdx.x * 256 + threadIdx.x;
  int s = perm_g(n);
  dst[n] = a[s] + b[s];
}

// f32 -> interleaved hi|lo bf16 [rows x 2048 u16] with chunk permute.
__global__ void conv_w(const float* __restrict__ src, int srcld, int coloff,
                       const int* __restrict__ gidx, int PERM, int rows,
                       u16* __restrict__ dst) {
  int idx = blockIdx.x * 256 + threadIdx.x;
  int r = idx >> 7, kc = (idx & 127) << 3;
  if (r >= rows) return;
  int s = gidx ? gidx[r] : (PERM ? perm_g(r) : r);
  const float* p = src + (size_t)s * srcld + coloff + kc;
  float4 v0 = *(const float4*)p, v1 = *(const float4*)(p + 4);
  float vv[8] = {v0.x, v0.y, v0.z, v0.w, v1.x, v1.y, v1.z, v1.w};
  u16 hi[8], lo[8];
#pragma unroll
  for (int i = 0; i < 8; ++i) {
    hi[i] = bf16_rn(vv[i]);
    lo[i] = bf16_rn(vv[i] - bf16_f(hi[i]));
  }
  u16x8 c0, c1;
#pragma unroll
  for (int i = 0; i < 4; ++i) {
    c0[2 * i] = hi[i];     c0[2 * i + 1] = lo[i];
    c1[2 * i] = hi[4 + i]; c1[2 * i + 1] = lo[4 + i];
  }
  int seg = kc >> 5;
  int ch0 = (kc >> 2) & 7;
  size_t base = (size_t)r * 2048 + seg * 64;
  *(u16x8*)&dst[base + (size_t)((ch0 ^ (r & 7)) << 3)] = c0;
  *(u16x8*)&dst[base + (size_t)(((ch0 | 1) ^ (r & 7)) << 3)] = c1;
}

// --------------- fp32 tiled GEMM (c0 init, optional dual store) ------------
template<int BM, int BN, int BK, int TM, int TN>
__launch_bounds__(256)
__global__ void gemm_nt(
    const float* __restrict__ A, const int* __restrict__ Aidx, int lda,
    const float* __restrict__ W, int ldw, int koff,
    const float* __restrict__ bias, float* __restrict__ C, float* __restrict__ C2,
    int ldc, int M, int N, int K) {
  constexpr int TX = BN / TN;
  constexpr int TY = BM / TM;
  static_assert(TX * TY == 256, "thread geometry");
  __shared__ float As[BK][BM + 4];
  __shared__ float Ws[BK][BN + 4];
  const int tid = threadIdx.x;
  const int tx = tid % TX, ty = tid / TX;
  const int m0 = blockIdx.y * BM, n0 = blockIdx.x * BN;
  float acc[TM][TN];
#pragma unroll
  for (int i = 0; i < TM; ++i)
#pragma unroll
    for (int j = 0; j < TN; ++j) acc[i][j] = 0.f;
  constexpr int AV = (BM * BK) / 4;
  constexpr int WV = (BN * BK) / 4;
  constexpr int KV = BK / 4;
  for (int k0 = 0; k0 < K; k0 += BK) {
#pragma unroll
    for (int lp = 0; lp < (AV + 255) / 256; ++lp) {
      int e = tid + lp * 256;
      if (e < AV) {
        int r = e / KV, kq = e % KV;
        int m = m0 + r;
        float4 v = make_float4(0.f, 0.f, 0.f, 0.f);
        if (m < M) {
          int row = Aidx ? Aidx[m] : m;
          v = *(const float4*)&A[(size_t)row * lda + k0 + kq * 4];
        }
        As[kq * 4 + 0][r] = v.x; As[kq * 4 + 1][r] = v.y;
        As[kq * 4 + 2][r] = v.z; As[kq * 4 + 3][r] = v.w;
      }
    }
#pragma unroll
    for (int lp = 0; lp < (WV + 255) / 256; ++lp) {
      int e = tid + lp * 256;
      if (e < WV) {
        int cc = e / KV, kq = e % KV;
        int n = n0 + cc;
        float4 v = make_float4(0.f, 0.f, 0.f, 0.f);
        if (n < N)
          v = *(const float4*)&W[(size_t)n * ldw + koff + k0 + kq * 4];
        Ws[kq * 4 + 0][cc] = v.x; Ws[kq * 4 + 1][cc] = v.y;
        Ws[kq * 4 + 2][cc] = v.z; Ws[kq * 4 + 3][cc] = v.w;
      }
    }
    __syncthreads();
#pragma unroll
    for (int kk = 0; kk < BK; ++kk) {
      float a[TM], b[TN];
#pragma unroll
      for (int i = 0; i < TM; ++i) a[i] = As[kk][ty * TM + i];
#pragma unroll
      for (int j = 0; j < TN; ++j) b[j] = Ws[kk][tx * TN + j];
#pragma unroll
      for (int i = 0; i < TM; ++i)
#pragma unroll
        for (int j = 0; j < TN; ++j)
          acc[i][j] += a[i] * b[j];
    }
    __syncthreads();
  }
#pragma unroll
  for (int i = 0; i < TM; ++i) {
    int m = m0 + ty * TM + i;
    if (m >= M) continue;
#pragma unroll
    for (int j = 0; j < TN; ++j) {
      int n = n0 + tx * TN + j;
      if (n >= N) continue;
      float v = acc[i][j];
      if (bias) v += bias[n];
      C[(size_t)m * ldc + n] = v;
      if (C2) C2[(size_t)m * ldc + n] = v;
    }
  }
}

// --------- pure-bf16 MFMA GEMM (round-11 single-buffered, proven) ----------
__launch_bounds__(256)
__global__ void gemm_bt(const u16* __restrict__ A, int Mrows,
                        const u16* __restrict__ Wb,
                        const float* __restrict__ bias,
                        const float* __restrict__ Dadd, int ldd, int dmask,
                        float* __restrict__ C, int ldc, int N, int nbx,
                        int mt, int ord) {
  __shared__ u16 lsA[128 * 64];
  __shared__ u16 lsB[128 * 64];

  int nwg = gridDim.x, bid = blockIdx.x;
  int q = nwg >> 3, r = nwg & 7;
  int xcd = bid & 7, base = bid >> 3;
  int wg = (xcd < r ? xcd * (q + 1) : r * (q + 1) + (xcd - r) * q) + base;
  int bx, by;
  if (ord) { by = wg % mt; bx = wg / mt; } else { bx = wg % nbx; by = wg / nbx; }
  const int m0 = by * 128, n0 = bx * 128;

  const int tid = threadIdx.x, w = tid >> 6, l = tid & 63;
  const int lr = l & 15, lq = l >> 4;
  const int wm = (w >> 1) * 64, wn = (w & 1) * 64;

  f32x4 acc[4][4] = {};

  for (int kt = 0; kt < 32; ++kt) {
#pragma unroll
    for (int i = 0; i < 4; ++i) {
      int rb = w * 32 + i * 8;
      int gm = m0 + rb + (l >> 3);
      if (gm > Mrows - 1) gm = Mrows - 1;
      const u16* ga = A + (size_t)gm * 2048 + kt * 64 + (l & 7) * 8;
      __builtin_amdgcn_global_load_lds(
          (const __attribute__((address_space(1))) void*)ga,
          (__attribute__((address_space(3))) void*)(lsA + rb * 64), 16, 0, 0);
      const u16* gb = Wb + (size_t)(n0 + rb + (l >> 3)) * 2048 + kt * 64 + (l & 7) * 8;
      __builtin_amdgcn_global_load_lds(
          (const __attribute__((address_space(1))) void*)gb,
          (__attribute__((address_space(3))) void*)(lsB + rb * 64), 16, 0, 0);
    }
    asm volatile("s_waitcnt vmcnt(0)" ::: "memory");
    __syncthreads();

    bf16x8 af[4][2], bfr[4][2];
#pragma unroll
    for (int i = 0; i < 4; ++i) {
      int ar = wm + i * 16 + lr;
#pragma unroll
      for (int s = 0; s < 2; ++s)
        af[i][s] = *(const bf16x8*)&lsA[ar * 64 + (((s << 2) + lq) ^ (ar & 7)) * 8];
    }
#pragma unroll
    for (int j = 0; j < 4; ++j) {
      int br = wn + j * 16 + lr;
#pragma unroll
      for (int s = 0; s < 2; ++s)
        bfr[j][s] = *(const bf16x8*)&lsB[br * 64 + (((s << 2) + lq) ^ (br & 7)) * 8];
    }
#pragma unroll
    for (int i = 0; i < 4; ++i)
#pragma unroll
      for (int j = 0; j < 4; ++j) {
        acc[i][j] = __builtin_amdgcn_mfma_f32_16x16x32_bf16(af[i][0], bfr[j][0], acc[i][j], 0, 0, 0);
        acc[i][j] = __builtin_amdgcn_mfma_f32_16x16x32_bf16(af[i][1], bfr[j][1], acc[i][j], 0, 0, 0);
      }
    __syncthreads();
  }

#pragma unroll
  for (int i = 0; i < 4; ++i) {
    int mbase = m0 + wm + i * 16 + lq * 4;
#pragma unroll
    for (int j = 0; j < 4; ++j) {
      int n = n0 + wn + j * 16 + lr;
      float badd = bias ? bias[n] : 0.f;
#pragma unroll
      for (int rr = 0; rr < 4; ++rr) {
        int m = mbase + rr;
        if (m >= Mrows) continue;
        float v = acc[i][j][rr] + badd;
        if (Dadd) {
          int dr = (dmask < 0) ? m : (m & dmask);
          v += Dadd[(size_t)dr * ldd + n];
        }
        C[(size_t)m * ldc + n] = v;
      }
    }
  }
}

// ----------- split-bf16 MFMA GEMM on f32 inputs (tier2/3 decoder) ----------
__launch_bounds__(256)
__global__ void gemm_sp(
    const float* __restrict__ A, int lda,
    const float* __restrict__ W, int ldw,
    const float* __restrict__ bias,
    float* __restrict__ C, int ldc, int M, int N, int K, int nbx) {
  __shared__ u16 As_h[128][40], As_l[128][40];
  __shared__ u16 Ws_h[128][40], Ws_l[128][40];
  int nwg = gridDim.x, bid = blockIdx.x;
  int q = nwg >> 3, r = nwg & 7;
  int xcd = bid & 7, base = bid >> 3;
  int wg = (xcd < r ? xcd * (q + 1) : r * (q + 1) + (xcd - r) * q) + base;
  int bx = wg % nbx, by = wg / nbx;
  const int m0 = by * 128, n0 = bx * 128;
  const int tid = threadIdx.x;
  const int wave = tid >> 6, lane = tid & 63;
  const int lr = lane & 15, lq = lane >> 4;
  const int wm = (wave >> 1) * 64, wn = (wave & 1) * 64;
  f32x4 acc[4][4] = {};
  for (int k0 = 0; k0 < K; k0 += 32) {
#pragma unroll
    for (int lp = 0; lp < 4; ++lp) {
      int s = tid + lp * 256;
      int row = s >> 3, kq = s & 7;
      float4 v = make_float4(0.f, 0.f, 0.f, 0.f);
      int gm = m0 + row;
      if (gm < M)
        v = *(const float4*)&A[(size_t)gm * lda + k0 + kq * 4];
      u16 h0 = bf16_rn(v.x), h1 = bf16_rn(v.y), h2 = bf16_rn(v.z), h3 = bf16_rn(v.w);
      u16 l0 = bf16_rn(v.x - bf16_f(h0)), l1 = bf16_rn(v.y - bf16_f(h1));
      u16 l2 = bf16_rn(v.z - bf16_f(h2)), l3 = bf16_rn(v.w - bf16_f(h3));
      *(uint2*)&As_h[row][kq * 4] =
          make_uint2((u32)h0 | ((u32)h1 << 16), (u32)h2 | ((u32)h3 << 16));
      *(uint2*)&As_l[row][kq * 4] =
          make_uint2((u32)l0 | ((u32)l1 << 16), (u32)l2 | ((u32)l3 << 16));
    }
#pragma unroll
    for (int lp = 0; lp < 4; ++lp) {
      int s = tid + lp * 256;
      int col = s >> 3, kq = s & 7;
      int n = n0 + col;
      float4 v = make_float4(0.f, 0.f, 0.f, 0.f);
      if (n < N)
        v = *(const float4*)&W[(size_t)n * ldw + k0 + kq * 4];
      u16 h0 = bf16_rn(v.x), h1 = bf16_rn(v.y), h2 = bf16_rn(v.z), h3 = bf16_rn(v.w);
      u16 l0 = bf16_rn(v.x - bf16_f(h0)), l1 = bf16_rn(v.y - bf16_f(h1));
      u16 l2 = bf16_rn(v.z - bf16_f(h2)), l3 = bf16_rn(v.w - bf16_f(h3));
      *(uint2*)&Ws_h[col][kq * 4] =
          make_uint2((u32)h0 | ((u32)h1 << 16), (u32)h2 | ((u32)h3 << 16));
      *(uint2*)&Ws_l[col][kq * 4] =
          make_uint2((u32)l0 | ((u32)l1 << 16), (u32)l2 | ((u32)l3 << 16));
    }
    __syncthreads();
    bf16x8 ah[4], al[4], bh[4], bl[4];
#pragma unroll
    for (int i = 0; i < 4; ++i) {
      ah[i] = *(const bf16x8*)&As_h[wm + i * 16 + lr][lq * 8];
      al[i] = *(const bf16x8*)&As_l[wm + i * 16 + lr][lq * 8];
    }
#pragma unroll
    for (int j = 0; j < 4; ++j) {
      bh[j] = *(const bf16x8*)&Ws_h[wn + j * 16 + lr][lq * 8];
      bl[j] = *(const bf16x8*)&Ws_l[wn + j * 16 + lr][lq * 8];
    }
#pragma unroll
    for (int i = 0; i < 4; ++i)
#pragma unroll
      for (int j = 0; j < 4; ++j) {
        acc[i][j] = __builtin_amdgcn_mfma_f32_16x16x32_bf16(ah[i], bh[j], acc[i][j], 0, 0, 0);
        acc[i][j] = __builtin_amdgcn_mfma_f32_16x16x32_bf16(ah[i], bl[j], acc[i][j], 0, 0, 0);
        acc[i][j] = __builtin_amdgcn_mfma_f32_16x16x32_bf16(al[i], bh[j], acc[i][j], 0, 0, 0);
      }
    __syncthreads();
  }
#pragma unroll
  for (int i = 0; i < 4; ++i) {
    int mbase = m0 + wm + i * 16 + lq * 4;
#pragma unroll
    for (int j = 0; j < 4; ++j) {
      int n = n0 + wn + j * 16 + lr;
      if (n >= N) continue;
      float badd = bias ? bias[n] : 0.f;
#pragma unroll
      for (int rr = 0; rr < 4; ++rr) {
        int m = mbase + rr;
        if (m >= M) continue;
        C[(size_t)m * ldc + n] = acc[i][j][rr] + badd;
      }
    }
  }
}

// ---------------- helpers for fused recurrence -----------------------------
__device__ __forceinline__ void gemm_half(
    const u32* __restrict__ hp, int rg, int w, int lr, int lq,
    const bf16x8 (&bfr)[8][4], f32x4 (&acc)[2][4]) {
  bf16x8 af[8][2];
#pragma unroll
  for (int s = 0; s < 8; ++s)
#pragma unroll
    for (int mt = 0; mt < 2; ++mt) {
      int m = rg * 32 + mt * 16 + lr;
      int seg = w * 4 + (s >> 1);
      int cis = ((((s & 1) << 2) + lq) ^ (lr & 7));
      const u32* p = hp + (size_t)m * 1024 + seg * 32 + cis * 4;
      asm volatile("global_load_dwordx4 %0, %1, off sc0 sc1"
                   : "=v"(af[s][mt]) : "v"(p) : "memory");
    }
  asm volatile("s_waitcnt vmcnt(0)" ::: "memory");
  __builtin_amdgcn_sched_barrier(0);
#pragma unroll
  for (int s = 0; s < 8; ++s)
#pragma unroll
    for (int mt = 0; mt < 2; ++mt)
#pragma unroll
      for (int nt = 0; nt < 4; ++nt)
        acc[mt][nt] = __builtin_amdgcn_mfma_f32_16x16x32_bf16(
            af[s][mt], bfr[s][nt], acc[mt][nt], 0, 0, 0);
}

// per-wave poll: wave w needs only writers ct in [8w, 8w+8) of its rg.
__device__ __forceinline__ void poll_src(const u32* flags, int rg, int w, int l, u32 tgt) {
  int guard = 0;
  for (;;) {
    u32 v = tgt;
    if (l < 8)
      v = __hip_atomic_load(flags + (size_t)((rg << 6) + (w << 3) + l) * 4,
                            __ATOMIC_RELAXED, __HIP_MEMORY_SCOPE_AGENT);
    if (__all(v >= tgt)) break;
    if (++guard > (1 << 23)) break;
    __builtin_amdgcn_s_sleep(1);
  }
}

// -------- fused dual-layer persistent recurrence (per-wave polling) --------
template<bool DUAL, bool EMIT>
__launch_bounds__(512, 1)
__global__ void rnn_dual(const u16* __restrict__ Whh0b, const u16* __restrict__ Whh1b,
                         const u16* __restrict__ Wih1b,
                         const float* __restrict__ xg0all, const float* __restrict__ bias1p,
                         float* __restrict__ cL0, float* __restrict__ hL0,
                         float* __restrict__ cL1, float* __restrict__ hL1,
                         u32* __restrict__ h0s, u32* __restrict__ h1s,
                         float* __restrict__ hsf,
                         u32* __restrict__ flg0, u32* __restrict__ flg1, int T) {
  __shared__ float partial[8][32][68];   // 69.6 KB

  const int bid = blockIdx.x;
  const int x = bid & 7, j = bid >> 3;
  const int layer = DUAL ? (j & 1) : 0;
  const int idx = DUAL ? (j >> 1) : j;
  const int ct = x * 8 + (idx & 7);
  const int rg = idx >> 3;
  const int tid = threadIdx.x, w = tid >> 6, l = tid & 63;
  const int lr = l & 15, lq = l >> 4;

  // ---- recurrent-W fragments (cached loads; L2-resident per XCD)
  const u16* WbA = (layer ? Whh1b : Whh0b) + (size_t)(ct * 64) * 2048;
  bf16x8 bfragA[8][4];
#pragma unroll
  for (int s = 0; s < 8; ++s)
#pragma unroll
    for (int nt = 0; nt < 4; ++nt) {
      int row = nt * 16 + lr;
      int seg = w * 4 + (s >> 1);
      int cis = ((((s & 1) << 2) + lq) ^ (lr & 7));
      bfragA[s][nt] = *(const bf16x8*)&WbA[(size_t)row * 2048 + seg * 64 + cis * 8];
    }
  // ---- layer-1 only: Wih1 fragments
  bf16x8 bfragX[8][4];
  if (DUAL && layer) {
    const u16* WbX = Wih1b + (size_t)(ct * 64) * 2048;
#pragma unroll
    for (int s = 0; s < 8; ++s)
#pragma unroll
      for (int nt = 0; nt < 4; ++nt) {
        int row = nt * 16 + lr;
        int seg = w * 4 + (s >> 1);
        int cis = ((((s & 1) << 2) + lq) ^ (lr & 7));
        bfragX[s][nt] = *(const bf16x8*)&WbX[(size_t)row * 2048 + seg * 64 + cis * 8];
      }
  }

  // cell mapping
  const int cm = tid >> 4, cu = tid & 15;
  const int m_c = rg * 32 + cm;
  const int unit = ct * 16 + cu;
  float* cL = layer ? cL1 : cL0;
  float* hL = layer ? hL1 : hL0;
  u32* hsl = layer ? h1s : h0s;
  u32* flgS = layer ? flg1 : flg0;
  float creg = cL[m_c * H_ + unit];
  float bset[4];
  if (layer) {
#pragma unroll
    for (int g = 0; g < 4; ++g)
      bset[g] = bias1p[ct * 64 + g * 16 + cu];
  }

  for (int t = 0; t < T; ++t) {
    float xgv[4];
    if (!layer) {
      const float* xg = xg0all + (size_t)t * ((size_t)B_ * G_);
#pragma unroll
      for (int g = 0; g < 4; ++g)
        xgv[g] = xg[(size_t)m_c * G_ + ct * 64 + g * 16 + cu];
    } else {
#pragma unroll
      for (int g = 0; g < 4; ++g) xgv[g] = bset[g];
    }

    f32x4 acc[2][4] = {};

    if (layer) {
      // phase 1: own-layer h1[t] (per-wave wait; overlaps layer-0 step t)
      if (t) poll_src(flg1, rg, w, l, (u32)t);
      gemm_half(h1s + (size_t)t * (B_ * 1024), rg, w, lr, lq, bfragA, acc);
      // phase 2: hs0[t] from layer-0
      poll_src(flg0, rg, w, l, (u32)(t + 1));
      gemm_half(h0s + (size_t)(t + 1) * (B_ * 1024), rg, w, lr, lq, bfragX, acc);
    } else {
      if (t) poll_src(flg0, rg, w, l, (u32)t);
      gemm_half(h0s + (size_t)t * (B_ * 1024), rg, w, lr, lq, bfragA, acc);
    }

    // ---- K-split reduction through LDS (per-wave region; barrier gates reads)
#pragma unroll
    for (int mt = 0; mt < 2; ++mt)
#pragma unroll
      for (int nt = 0; nt < 4; ++nt)
#pragma unroll
        for (int rr = 0; rr < 4; ++rr)
          partial[w][mt * 16 + lq * 4 + rr][nt * 16 + lr] = acc[mt][nt][rr];
    __syncthreads();

    // ---- cell
    float g4[4];
#pragma unroll
    for (int g = 0; g < 4; ++g) {
      float ssum = xgv[g];
#pragma unroll
      for (int p = 0; p < 8; ++p) ssum += partial[p][cm][g * 16 + cu];
      g4[g] = ssum;
    }
    float cn = sigm(g4[1]) * creg + sigm(g4[0]) * tanhf(g4[2]);
    float hn = sigm(g4[3]) * tanhf(cn);
    creg = cn;
    if (EMIT && layer) hsf[(size_t)t * (B_ * H_) + m_c * H_ + unit] = hn;
    if (t == T - 1) { cL[m_c * H_ + unit] = cn; hL[m_c * H_ + unit] = hn; }
    u16 hh = bf16_rn(hn);
    u16 hl2 = bf16_rn(hn - bf16_f(hh));
    u32 packed = (u32)hh | ((u32)hl2 << 16);
    u32* hnext = hsl + (size_t)(t + 1) * (B_ * 1024);
    u32 hidx = m_c * 1024 + ((unit >> 5) << 5) +
               ((((unit >> 2) & 7) ^ (m_c & 7)) << 2) + (unit & 3);
    {
      u32* sp = hnext + hidx;
      asm volatile("global_store_dword %0, %1, off sc0 sc1"
                   :: "v"(sp), "v"(packed) : "memory");
    }

    // ---- publish (layer-0 always: layer-1 consumes even the last slot)
    if (!layer || t < T - 1) {
      asm volatile("s_waitcnt vmcnt(0)" ::: "memory");
      __syncthreads();
      if (tid == 0)
        __hip_atomic_store(flgS + (size_t)((rg << 6) + ct) * 4, (u32)(t + 1),
                           __ATOMIC_RELAXED, __HIP_MEMORY_SCOPE_AGENT);
    }
  }
}

// --------- single-step kernel (tiny-ws fallback), perm_g cell --------------
__launch_bounds__(256)
__global__ void rnn_step(const u16* __restrict__ hprev, const u16* __restrict__ Wb,
                         const float* __restrict__ xg,
                         float* __restrict__ c, float* __restrict__ hf,
                         u32* __restrict__ hout) {
  __shared__ char smem[32768];
  u16* lsA = (u16*)smem;
  u16* lsB = (u16*)(smem + 16384);
  const int nt = blockIdx.x, n0 = nt * 64;
  const int tid = threadIdx.x, w = tid >> 6, l = tid & 63;
  const int lr = l & 15, lq = l >> 4;
  f32x4 acc[4] = {};
  for (int kt = 0; kt < 16; ++kt) {
#pragma unroll
    for (int i = 0; i < 4; ++i) {
      int rb = w * 16 + i * 4;
      const u16* ga = hprev + (size_t)(rb + (l >> 4)) * 2048 + kt * 128 + (l & 15) * 8;
      __builtin_amdgcn_global_load_lds(
          (const __attribute__((address_space(1))) void*)ga,
          (__attribute__((address_space(3))) void*)(lsA + rb * 128), 16, 0, 0);
      const u16* gb = Wb + (size_t)(n0 + rb + (l >> 4)) * 2048 + kt * 128 + (l & 15) * 8;
      __builtin_amdgcn_global_load_lds(
          (const __attribute__((address_space(1))) void*)gb,
          (__attribute__((address_space(3))) void*)(lsB + rb * 128), 16, 0, 0);
    }
    asm volatile("s_waitcnt vmcnt(0)" ::: "memory");
    __syncthreads();
    bf16x8 af[4];
    int ar = w * 16 + lr;
#pragma unroll
    for (int s = 0; s < 4; ++s)
      af[s] = *(const bf16x8*)&lsA[ar * 128 + (s >> 1) * 64 + ((((s & 1) << 2) + lq) ^ (ar & 7)) * 8];
#pragma unroll
    for (int jj = 0; jj < 4; ++jj) {
      int br = jj * 16 + lr;
#pragma unroll
      for (int s = 0; s < 4; ++s) {
        bf16x8 bv = *(const bf16x8*)&lsB[br * 128 + (s >> 1) * 64 + ((((s & 1) << 2) + lq) ^ (br & 7)) * 8];
        acc[jj] = __builtin_amdgcn_mfma_f32_16x16x32_bf16(af[s], bv, acc[jj], 0, 0, 0);
      }
    }
    __syncthreads();
  }
  float* gsh = (float*)smem;
#pragma unroll
  for (int jj = 0; jj < 4; ++jj)
#pragma unroll
    for (int rr = 0; rr < 4; ++rr)
      gsh[(w * 16 + lq * 4 + rr) * 68 + jj * 16 + lr] = acc[jj][rr];
  __syncthreads();
  const int ui = tid & 15, mq = tid >> 4;
#pragma unroll
  for (int mr = 0; mr < 4; ++mr) {
    int m = mr * 16 + mq;
    float gi = gsh[m * 68 + 0 + ui]  + xg[(size_t)m * G_ + n0 + 0 + ui];
    float gf = gsh[m * 68 + 16 + ui] + xg[(size_t)m * G_ + n0 + 16 + ui];
    float gg = gsh[m * 68 + 32 + ui] + xg[(size_t)m * G_ + n0 + 32 + ui];
    float go = gsh[m * 68 + 48 + ui] + xg[(size_t)m * G_ + n0 + 48 + ui];
    int unit = nt * 16 + ui;
    int ci = m * H_ + unit;
    float cn = sigm(gf) * c[ci] + sigm(gi) * tanhf(gg);
    float hn = sigm(go) * tanhf(cn);
    c[ci] = cn;
    hf[ci] = hn;
    u16 hh = bf16_rn(hn);
    u16 hl = bf16_rn(hn - bf16_f(hh));
    u32 hidx = m * 1024 + ((unit >> 5) << 5) +
               ((((unit >> 2) & 7) ^ (m & 7)) << 2) + (unit & 3);
    hout[hidx] = (u32)hh | ((u32)hl << 16);
  }
}

// ---------------------------------------------------------------------------
extern "C" void kernel_launch(void* const* d_in, const int* in_sizes, int n_in,
                              void* d_out, int out_size, void* d_ws, size_t ws_size,
                              hipStream_t stream) {
  const int*   word  = (const int*)  d_in[0];
  const int*   seq   = (const int*)  d_in[1];
  const float* emb   = (const float*)d_in[2];
  const float* w2h_W = (const float*)d_in[3];
  const float* w2h_b = (const float*)d_in[4];
  const float* W_ih0 = (const float*)d_in[5];
  const float* W_hh0 = (const float*)d_in[6];
  const float* b_ih0 = (const float*)d_in[7];
  const float* b_hh0 = (const float*)d_in[8];
  const float* W_ih1 = (const float*)d_in[9];
  const float* W_hh1 = (const float*)d_in[10];
  const float* b_ih1 = (const float*)d_in[11];
  const float* b_hh1 = (const float*)d_in[12];
  const float* dec_W = (const float*)d_in[13];
  const float* dec_b = (const float*)d_in[14];

  float* out = (float*)d_out;
  float* hL0 = out + 102400000;
  float* hL1 = hL0 + B_ * H_;
  float* cL0 = out + 102531072;
  float* cL1 = cL0 + B_ * H_;

  // scratch in d_out (clobber-safe: decoder writes [0,102.4M) last)
  float* xg0      = out;                       // [3200,4096]
  u16*   x0w_bf   = (u16*)(out + 13200000);    // [64,2048]
  u16*   x0seq_bf = (u16*)(out + 13300000);    // [3200,2048]
  u32*   hs0slots = (u32*)(out + 16600000);    // [51][64][1024] u32-packed
  u16*   wih0a_bf = (u16*)(out + 20000000);    // [4096,2048] each
  u16*   wih0b_bf = (u16*)(out + 24200000);
  u16*   wih1_bf  = (u16*)(out + 28400000);
  u16*   whh0_bf  = (u16*)(out + 32600000);
  u16*   whh1_bf  = (u16*)(out + 36800000);
  float* y_w      = out + 73800000;            // [64,4096]
  float* bias0p   = out + 74400000;
  float* bias1p   = out + 74410000;
  float* xg1      = out + 87560192;            // tier3 only
  u32*   h1alt    = (u32*)(out + 91000000);    // tier2 h1 slots [51][64][1024]
  u32*   flg0     = (u32*)(out + 101000000);   // 128 flags x 4 u32 (16B stride)
  u32*   flg1     = (u32*)(out + 101004096);
  u32*   hbfA     = (u32*)(out + 101100000);   // tier3 ping-pong
  u32*   hbfB     = (u32*)(out + 101200000);

  const size_t need_hs1  = (size_t)T_ * B_ * H_ * 4;
  const size_t need_full = (size_t)V_ * 2048 * 2 + (size_t)(T_ + 1) * B_ * 1024 * 4;
  const bool tier1 = ws_size >= need_full;
  const bool tier2 = !tier1 && ws_size >= need_hs1;

  u16*   decW_bf  = (u16*)d_ws;
  u32*   hs1slots = (u32*)d_ws + (size_t)V_ * 1024;
  float* hs1f     = (float*)d_ws;

  // init
  fill_zero<<<32, 256, 0, stream>>>(out + 101000000, 8192);       // both flag sets
  fill_zero<<<256, 256, 0, stream>>>((float*)hs0slots, 65536);    // h0 slot 0
  if (tier1) fill_zero<<<256, 256, 0, stream>>>((float*)hs1slots, 65536);
  else if (tier2) fill_zero<<<256, 256, 0, stream>>>((float*)h1alt, 65536);
  bias_perm<<<16, 256, 0, stream>>>(b_ih0, b_hh0, bias0p);
  bias_perm<<<16, 256, 0, stream>>>(b_ih1, b_hh1, bias1p);

  // c0 = word_emb @ w2h_W^T + w2h_b  (identical for both layers: dual store)
  gemm_nt<64, 64, 16, 4, 4><<<dim3(16, 1), 256, 0, stream>>>(
      emb, word, E_, w2h_W, E_, 0, w2h_b, cL0, cL1, H_, B_, H_, E_);

  // conversions to interleaved hi|lo bf16 (chunk-permuted; weights perm_g)
  conv_w<<<2048, 256, 0, stream>>>(W_ih0, 2 * E_, 0,  nullptr, 1, G_, wih0a_bf);
  conv_w<<<2048, 256, 0, stream>>>(W_ih0, 2 * E_, E_, nullptr, 1, G_, wih0b_bf);
  conv_w<<<2048, 256, 0, stream>>>(W_ih1, H_, 0, nullptr, 1, G_, wih1_bf);
  conv_w<<<2048, 256, 0, stream>>>(W_hh0, H_, 0, nullptr, 1, G_, whh0_bf);
  conv_w<<<2048, 256, 0, stream>>>(W_hh1, H_, 0, nullptr, 1, G_, whh1_bf);
  conv_w<<<32,   256, 0, stream>>>(emb, E_, 0, word, 0, B_, x0w_bf);
  conv_w<<<1600, 256, 0, stream>>>(emb, E_, 0, seq, 0, T_ * B_, x0seq_bf);
  if (tier1)
    conv_w<<<16000, 256, 0, stream>>>(dec_W, H_, 0, nullptr, 0, V_, decW_bf);

  // y_w, xg0
  gemm_bt<<<32, 256, 0, stream>>>(x0w_bf, B_, wih0a_bf, bias0p,
                                  nullptr, 0, -1, y_w, G_, G_, 32, 1, 0);
  gemm_bt<<<800, 256, 0, stream>>>(x0seq_bf, T_ * B_, wih0b_bf, nullptr,
                                   y_w, G_, 63, xg0, G_, G_, 32, 25, 0);

  if (tier1) {
    rnn_dual<true, false><<<256, 512, 0, stream>>>(
        whh0_bf, whh1_bf, wih1_bf, xg0, bias1p,
        cL0, hL0, cL1, hL1, hs0slots, hs1slots, nullptr, flg0, flg1, T_);
    gemm_bt<<<6250, 256, 0, stream>>>((const u16*)(hs1slots + (size_t)B_ * 1024),
                                      T_ * B_, decW_bf, dec_b,
                                      nullptr, 0, -1, out, V_, V_, 250, 25, 1);
  } else if (tier2) {
    rnn_dual<true, true><<<256, 512, 0, stream>>>(
        whh0_bf, whh1_bf, wih1_bf, xg0, bias1p,
        cL0, hL0, cL1, hL1, hs0slots, h1alt, hs1f, flg0, flg1, T_);
    gemm_sp<<<6250, 256, 0, stream>>>(
        hs1f, H_, dec_W, H_, dec_b, out, V_, T_ * B_, V_, H_, 250);
  } else {
    // tier3: layer-0 solo persistent, then sequential layer-1 + decode
    rnn_dual<false, false><<<128, 512, 0, stream>>>(
        whh0_bf, whh1_bf, wih1_bf, xg0, bias1p,
        cL0, hL0, cL1, hL1, hs0slots, nullptr, nullptr, flg0, flg1, T_);
    gemm_bt<<<800, 256, 0, stream>>>((const u16*)(hs0slots + (size_t)B_ * 1024),
                                     T_ * B_, wih1_bf, bias1p,
                                     nullptr, 0, -1, xg1, G_, G_, 32, 25, 0);
    for (int t = 0; t < T_; ++t) {
      const u16* hp = t ? (const u16*)((t & 1) ? hbfA : hbfB) : (const u16*)hs0slots;
      u32* ho = (t & 1) ? hbfB : hbfA;
      rnn_step<<<64, 256, 0, stream>>>(
          hp, whh1_bf, xg1 + (size_t)t * B_ * G_, cL1, hL1, ho);
      gemm_sp<<<250, 256, 0, stream>>>(
          hL1, H_, dec_W, H_, dec_b, out + (size_t)t * B_ * V_, V_, B_, V_, H_, 250);
    }
  }
}